// Round 6
// baseline (288.013 us; speedup 1.0000x reference)
//
#include <hip/hip_runtime.h>

// SNN forward, round 6.
// convD: persistent blocks (1/CU), cross-item double-buffered LDS staging —
// item k+1's global spike loads are in flight during item k's MFMA section.
// Inner MFMA loop identical to round 3 (compiler-scheduled; round 5 showed
// manual reg pipelining hurts). Accumulation order unchanged -> identical u.
// LIF kernels: unroll-16. prep merged into one launch.

typedef __attribute__((ext_vector_type(8))) _Float16 v8h;
typedef __attribute__((ext_vector_type(16))) float v16f;
typedef _Float16 half_t;

#define NB 32
#define NC 64
#define NT 129
#define TIN 128
#define NM 40
#define MSTR 136          // LDS per-slot stride: conflict-free (0 conflicts measured)
#define SROWB 5120        // global spike row bytes = 40*64*2

// ---- weights -> MFMA A-fragments, 4 replicated copies, both layers in one launch ----
__global__ void prep_wfrag2(const float* __restrict__ w2, const float* __restrict__ w3,
                            uint4* __restrict__ wfA, uint4* __restrict__ wfB) {
    int tid = blockIdx.x * 256 + threadIdx.x;   // 24576
    if (tid >= 24576) return;
    const float* w = (tid < 12288) ? w2 : w3;
    uint4* wf = (tid < 12288) ? wfA : wfB;
    int t2 = (tid < 12288) ? tid : tid - 12288;
    int lane = t2 & 63;
    int rest = t2 >> 6;
    int hl = rest & 1;
    int ct = (rest >> 1) & 1;
    int cq = (rest >> 2) & 3;
    int tap = rest >> 4;
    int kh = tap / 3, kw = tap % 3;
    int co = ct * 32 + (lane & 31);
    unsigned short o[8];
#pragma unroll
    for (int jj = 0; jj < 8; jj++) {
        int ci = cq * 16 + (lane >> 5) * 8 + jj;
        float wv = w[((co * 64 + ci) * 4 + kh) * 3 + kw];
        _Float16 hi = (_Float16)wv;
        _Float16 val = hl ? (_Float16)((wv - (float)hi) * 2048.0f) : hi;
        unsigned short us;
        __builtin_memcpy(&us, &val, 2);
        o[jj] = us;
    }
    uint4 r;
    __builtin_memcpy(&r, o, 16);
#pragma unroll
    for (int c = 0; c < 4; c++) wf[c * 12288 + t2] = r;
}

// ---- conv1 (1->64ch, 4x3, pad(2,1)) + LIF1, unroll-8 row prefetch ----
__global__ void conv1_lif1(const float* __restrict__ x, const float* __restrict__ w1,
                           half_t* __restrict__ s1) {
    const int mg = blockIdx.x;        // 0..9
    const int b = blockIdx.y;
    const int c = threadIdx.x & 63;
    const int ml = threadIdx.x >> 6;  // 0..3
    const int m = mg * 4 + ml;
    float w[4][3];
#pragma unroll
    for (int kh = 0; kh < 4; kh++)
#pragma unroll
        for (int kw = 0; kw < 3; kw++) w[kh][kw] = w1[(c * 4 + kh) * 3 + kw];
    const float* xb = x + (size_t)b * TIN * NM;

    float xw[12][3];
#pragma unroll
    for (int rr = 0; rr < 12; rr++)
#pragma unroll
        for (int kw = 0; kw < 3; kw++) xw[rr][kw] = 0.f;
#pragma unroll
    for (int rr = 2; rr < 4; rr++)
#pragma unroll
        for (int kw = 0; kw < 3; kw++) {
            int mc = m - 1 + kw;
            xw[rr][kw] = ((unsigned)mc < (unsigned)NM) ? xb[(rr - 2) * NM + mc] : 0.f;
        }

    half_t* orow = s1 + ((size_t)b * NT * NM + m) * 64 + c;
    float v = 0.f;
    const float TAUc = 10.0f / 7.0f;

    for (int tb = 0; tb < NT; tb += 8) {
#pragma unroll
        for (int q = 0; q < 8; q++) {
            int row = tb + 2 + q;
#pragma unroll
            for (int kw = 0; kw < 3; kw++) {
                int mc = m - 1 + kw;
                xw[4 + q][kw] = (row < TIN && (unsigned)mc < (unsigned)NM)
                                    ? xb[row * NM + mc] : 0.f;
            }
        }
        int kmax = (NT - tb) < 8 ? (NT - tb) : 8;
#pragma unroll
        for (int k = 0; k < 8; k++) {
            if (k < kmax) {
                float uacc = 0.f;
#pragma unroll
                for (int kh = 0; kh < 4; kh++)
#pragma unroll
                    for (int kw = 0; kw < 3; kw++) uacc += xw[k + kh][kw] * w[kh][kw];
                v = v + (uacc - v) / TAUc;
                float s = (v >= 1.0f) ? 1.0f : 0.0f;
                orow[(size_t)(tb + k) * NM * 64] = (half_t)s;
                if (v >= 1.0f) v = 0.0f;
            }
        }
#pragma unroll
        for (int rr = 0; rr < 4; rr++)
#pragma unroll
            for (int kw = 0; kw < 3; kw++) xw[rr][kw] = xw[8 + rr][kw];
    }
}

// ---- item decode: g -> (b, r, j0) ----
template <int RSH>
__device__ __forceinline__ void decode_item(int g, int& b, int& r, int& j0) {
    int bx = g % 33;
    b = g / 33;
    if (bx < 32) { r = bx & ((1 << RSH) - 1); j0 = (bx >> RSH) * 4; }
    else         { r = 0;                     j0 = (32 >> RSH) * 4; }
}

template <int DH, int PH, int PW, int EXT, int NREG>
__device__ __forceinline__ void stage_regs(uint4* R, const half_t* __restrict__ spk,
                                           int b, int r, int j0, int tid) {
    constexpr int NCH = 7 * EXT * 8;
    const char* spb = (const char*)spk + (size_t)b * NT * SROWB;
#pragma unroll
    for (int k = 0; k < NREG; k++) {
        int c = tid + k * 256;
        uint4 val = make_uint4(0u, 0u, 0u, 0u);
        if (c < NCH) {
            int i = c / (EXT * 8);
            int rem = c - i * (EXT * 8);
            int s = rem >> 3;
            int ci8 = rem & 7;
            int tg = r - PH + DH * (j0 + i);
            int md = s - PW;
            if ((unsigned)tg < (unsigned)NT && (unsigned)md < (unsigned)NM)
                val = *(const uint4*)(spb + ((size_t)tg * NM + md) * 128 + ci8 * 16);
        }
        R[k] = val;
    }
}

template <int EXT, int NREG>
__device__ __forceinline__ void write_lds(const uint4* R, char* buf, int tid) {
    constexpr int NCH = 7 * EXT * 8;
#pragma unroll
    for (int k = 0; k < NREG; k++) {
        int c = tid + k * 256;
        if (c < NCH) {
            int i = c / (EXT * 8);
            int rem = c - i * (EXT * 8);
            int s = rem >> 3;
            int ci8 = rem & 7;
            *(uint4*)(buf + i * (EXT * MSTR) + s * MSTR + ci8 * 16) = R[k];
        }
    }
}

// ---- persistent double-buffered MFMA conv ----
template <int DH, int PH, int DW, int PW, int EXT, int RSH, int NREG>
__global__ __launch_bounds__(256, 1) void convD(const half_t* __restrict__ spk,
                                                const uint4* __restrict__ wfrag,
                                                float* __restrict__ u, int totItems) {
    extern __shared__ char lds[];
    constexpr int LROWB = EXT * MSTR;
    constexpr int LHALF = 7 * LROWB;
    const int tid = threadIdx.x;
    const int lane = tid & 63;
    const int wv = tid >> 6;

    // lane decode (item-independent)
    const int pos = lane & 31;
    const int jlocal = pos >> 4;
    const int mloc = pos & 15;
    const int hseg = lane >> 5;
    int baseB[2], mm[2], jdec[2];
    bool tvalid[2];
#pragma unroll
    for (int pt = 0; pt < 2; pt++) {
        int tau = 2 * wv + pt;
        tvalid[pt] = (tau <= 5);
        int tauc = tvalid[pt] ? tau : 5;
        int jp = tauc / 3;
        int mc = tauc - 3 * jp;
        int j = 2 * jp + jlocal;                // 0..3
        int m = mc * 16 + mloc;                 // 0..47
        int meff = m > 39 ? 39 : m;
        mm[pt] = m;
        jdec[pt] = j;
        baseB[pt] = j * LROWB + meff * MSTR + hseg * 16;
    }

    // first item
    int g = blockIdx.x;
    int cb, cr, cj0;
    decode_item<RSH>(g, cb, cr, cj0);
    uint4 R[NREG];
    stage_regs<DH, PH, PW, EXT, NREG>(R, spk, cb, cr, cj0, tid);
    write_lds<EXT, NREG>(R, lds, tid);
    __syncthreads();

    int bufsel = 0;
    const float invs = 1.0f / 2048.0f;
    while (true) {
        int gn = g + (int)gridDim.x;
        bool hn = gn < totItems;
        int nb = 0, nr = 0, nj0 = 0;
        if (hn) {                               // issue next item's loads NOW
            decode_item<RSH>(gn, nb, nr, nj0);
            stage_regs<DH, PH, PW, EXT, NREG>(R, spk, nb, nr, nj0, tid);
        }

        // ---- MFMA section on current item (overlaps in-flight loads) ----
        v16f acc[2][2][2];
#pragma unroll
        for (int a = 0; a < 2; a++)
#pragma unroll
            for (int c = 0; c < 2; c++)
#pragma unroll
                for (int h = 0; h < 2; h++) acc[a][c][h] = (v16f)(0.0f);

        const char* buf = lds + bufsel * LHALF;
        const uint4* wp = wfrag + ((size_t)(g & 3)) * 12288 + lane;
#pragma unroll
        for (int tap = 0; tap < 12; tap++) {
            const int kh = tap / 3, kw = tap % 3;
            const int bo = kh * LROWB + kw * (DW * MSTR);
#pragma unroll
            for (int cq = 0; cq < 4; cq++) {
                v8h B0 = *(const v8h*)(buf + baseB[0] + bo + cq * 32);
                v8h B1 = *(const v8h*)(buf + baseB[1] + bo + cq * 32);
                const uint4* wq = wp + (tap * 4 + cq) * 256;
                v8h A00 = *(const v8h*)(wq);
                v8h A01 = *(const v8h*)(wq + 64);
                v8h A10 = *(const v8h*)(wq + 128);
                v8h A11 = *(const v8h*)(wq + 192);
                acc[0][0][0] = __builtin_amdgcn_mfma_f32_32x32x16_f16(A00, B0, acc[0][0][0], 0, 0, 0);
                acc[0][0][1] = __builtin_amdgcn_mfma_f32_32x32x16_f16(A01, B0, acc[0][0][1], 0, 0, 0);
                acc[0][1][0] = __builtin_amdgcn_mfma_f32_32x32x16_f16(A10, B0, acc[0][1][0], 0, 0, 0);
                acc[0][1][1] = __builtin_amdgcn_mfma_f32_32x32x16_f16(A11, B0, acc[0][1][1], 0, 0, 0);
                acc[1][0][0] = __builtin_amdgcn_mfma_f32_32x32x16_f16(A00, B1, acc[1][0][0], 0, 0, 0);
                acc[1][0][1] = __builtin_amdgcn_mfma_f32_32x32x16_f16(A01, B1, acc[1][0][1], 0, 0, 0);
                acc[1][1][0] = __builtin_amdgcn_mfma_f32_32x32x16_f16(A10, B1, acc[1][1][0], 0, 0, 0);
                acc[1][1][1] = __builtin_amdgcn_mfma_f32_32x32x16_f16(A11, B1, acc[1][1][1], 0, 0, 0);
            }
        }

        // ---- write next item's staged data, release barrier ----
        if (hn) write_lds<EXT, NREG>(R, lds + (bufsel ^ 1) * LHALF, tid);
        __syncthreads();

        // ---- epilogue for current item (stores overlap next MFMA section) ----
#pragma unroll
        for (int pt = 0; pt < 2; pt++) {
            int t = cr + DH * (cj0 + jdec[pt]);
            if (tvalid[pt] && mm[pt] < NM && t < NT) {
                float* base = u + ((size_t)(cb * NT + t) * NM + mm[pt]) * 64;
#pragma unroll
                for (int ct = 0; ct < 2; ct++) {
#pragma unroll
                    for (int gg = 0; gg < 4; gg++) {
                        int co = ct * 32 + 8 * gg + 4 * hseg;
                        float4 val;
                        val.x = acc[pt][ct][0][4 * gg + 0] + acc[pt][ct][1][4 * gg + 0] * invs;
                        val.y = acc[pt][ct][0][4 * gg + 1] + acc[pt][ct][1][4 * gg + 1] * invs;
                        val.z = acc[pt][ct][0][4 * gg + 2] + acc[pt][ct][1][4 * gg + 2] * invs;
                        val.w = acc[pt][ct][0][4 * gg + 3] + acc[pt][ct][1][4 * gg + 3] * invs;
                        *(float4*)(base + co) = val;
                    }
                }
            }
        }

        if (!hn) break;
        g = gn; cb = nb; cr = nr; cj0 = nj0; bufsel ^= 1;
    }
}

// ---- LIF over T: u fp32 -> compact f16 spikes, unroll-16 ----
__global__ void lif_spikes(const float* __restrict__ u, half_t* __restrict__ s2) {
    int tid = blockIdx.x * 256 + threadIdx.x;   // 81920
    int b = tid / 2560;
    int cm = tid % 2560;
    const float* up = u + (size_t)b * NT * 2560 + cm;
    half_t* sp = s2 + (size_t)b * NT * 2560 + cm;
    float v = 0.f;
    const float TAUc = 10.0f / 7.0f;
    for (int tb = 0; tb < 128; tb += 16) {
        float uu[16];
#pragma unroll
        for (int k = 0; k < 16; k++) uu[k] = up[(size_t)(tb + k) * 2560];
#pragma unroll
        for (int k = 0; k < 16; k++) {
            v = v + (uu[k] - v) / TAUc;
            float s = (v >= 1.0f) ? 1.0f : 0.0f;
            sp[(size_t)(tb + k) * 2560] = (half_t)s;
            if (v >= 1.0f) v = 0.f;
        }
    }
    float uu = up[(size_t)128 * 2560];
    v = v + (uu - v) / TAUc;
    sp[(size_t)128 * 2560] = (half_t)((v >= 1.0f) ? 1.0f : 0.0f);
}

// ---- LIF3: spike counts only (mean commutes with FC), unroll-16 ----
__global__ void lif_sum(const float* __restrict__ u, float* __restrict__ hsum) {
    int tid = blockIdx.x * 256 + threadIdx.x;   // 81920
    int b = tid / 2560;
    int cm = tid % 2560;                         // = m*64 + co
    int m = cm >> 6;
    int co = cm & 63;
    const float* up = u + (size_t)b * NT * 2560 + cm;
    float v = 0.f, cnt = 0.f;
    const float TAUc = 10.0f / 7.0f;
    for (int tb = 0; tb < 128; tb += 16) {
        float uu[16];
#pragma unroll
        for (int k = 0; k < 16; k++) uu[k] = up[(size_t)(tb + k) * 2560];
#pragma unroll
        for (int k = 0; k < 16; k++) {
            v = v + (uu[k] - v) / TAUc;
            if (v >= 1.0f) { cnt += 1.0f; v = 0.f; }
        }
    }
    float uu = up[(size_t)128 * 2560];
    v = v + (uu - v) / TAUc;
    if (v >= 1.0f) cnt += 1.0f;
    hsum[b * 2560 + co * NM + m] = cnt;          // feature index = c*40 + m
}

// ---- FC on counts: y[b,k] = bf[k] + (sum_cm cnt*wf[k,cm]) / 129 ----
__global__ void fc_out(const float* __restrict__ hsum, const float* __restrict__ wf,
                       const float* __restrict__ bfv, float* __restrict__ out) {
    int b = blockIdx.x;
    int tid = threadIdx.x;
    float p[12];
#pragma unroll
    for (int k = 0; k < 12; k++) p[k] = 0.0f;
    for (int cm = tid; cm < NC * NM; cm += 256) {
        float h = hsum[b * NC * NM + cm];
#pragma unroll
        for (int k = 0; k < 12; k++) p[k] += h * wf[k * (NC * NM) + cm];
    }
    __shared__ float red[12][4];
    int lane = tid & 63, w = tid >> 6;
#pragma unroll
    for (int k = 0; k < 12; k++) {
        float s = p[k];
#pragma unroll
        for (int off = 32; off > 0; off >>= 1) s += __shfl_down(s, off, 64);
        if (lane == 0) red[k][w] = s;
    }
    __syncthreads();
    if (tid < 12) {
        float s = red[tid][0] + red[tid][1] + red[tid][2] + red[tid][3];
        out[b * 12 + tid] = bfv[tid] + s / 129.0f;
    }
}

extern "C" void kernel_launch(void* const* d_in, const int* in_sizes, int n_in,
                              void* d_out, int out_size, void* d_ws, size_t ws_size,
                              hipStream_t stream) {
    const float* x  = (const float*)d_in[0];
    const float* w1 = (const float*)d_in[1];
    const float* w2 = (const float*)d_in[2];
    const float* w3 = (const float*)d_in[3];
    const float* wf = (const float*)d_in[4];
    const float* bf = (const float*)d_in[5];
    float* out = (float*)d_out;

    char* ws = (char*)d_ws;
    half_t* s1  = (half_t*)ws;                      // 21,135,360 B
    half_t* s2  = (half_t*)(ws + 21135360);         // 21,135,360 B
    float*  u   = (float*)(ws + 42270720);          // 42,270,720 B
    uint4*  wf2 = (uint4*)(ws + 84541440);          // 786,432 B (4 copies)
    uint4*  wf3 = (uint4*)(ws + 85327872);          // 786,432 B (4 copies)
    float* hsum = (float*)(ws + 86114304);          // 327,680 B

    // layer 2: EXT=46 -> LHALF=43792, dbuf=87,584 B; NREG=ceil(2576/256)=11
    // layer 3: EXT=58 -> LHALF=55216, dbuf=110,432 B; NREG=ceil(3248/256)=13
    constexpr int LDS2 = 2 * 7 * 46 * MSTR;
    constexpr int LDS3 = 2 * 7 * 58 * MSTR;
    static bool attr_set = false;
    if (!attr_set) {
        hipFuncSetAttribute((const void*)&convD<4, 6, 3, 3, 46, 2, 11>,
                            hipFuncAttributeMaxDynamicSharedMemorySize, LDS2);
        hipFuncSetAttribute((const void*)&convD<16, 24, 9, 9, 58, 4, 13>,
                            hipFuncAttributeMaxDynamicSharedMemorySize, LDS3);
        attr_set = true;
    }

    prep_wfrag2<<<96, 256, 0, stream>>>(w2, w3, wf2, wf3);

    conv1_lif1<<<dim3(10, 32), 256, 0, stream>>>(x, w1, s1);

    convD<4, 6, 3, 3, 46, 2, 11><<<256, 256, LDS2, stream>>>(s1, wf2, u, 1056);
    lif_spikes<<<320, 256, 0, stream>>>(u, s2);

    convD<16, 24, 9, 9, 58, 4, 13><<<256, 256, LDS3, stream>>>(s2, wf3, u, 1056);
    lif_sum<<<320, 256, 0, stream>>>(u, hsum);

    fc_out<<<32, 256, 0, stream>>>(hsum, wf, bf, out);
}